// Round 5
// baseline (1879.624 us; speedup 1.0000x reference)
//
#include <hip/hip_runtime.h>
#include <stdint.h>

// JAX jax_threefry_partitionable=True semantics (verified exact, rounds 1-4).
// Round-5: the single-workgroup sim no longer writes the big p/s output rows (that made
// it write-BW-bound on one CU, ~185us). It emits only a compact trace per step:
// nv[t][n] (uint16) + state code st[t][n] (uint8). A full-chip k_expand then replays the
// per-node p-chain (bit-identical float op sequence) and writes all output rows at HBM BW.
constexpr int NN = 10000;          // nodes
constexpr int EE = 1000;           // hyperedges
constexpr int TT = 30;             // output rows
constexpr int TS = TT - 1;         // simulated steps
constexpr int ROW = NN * 3;        // floats per output row
constexpr int S_OFF = TT * ROW;    // state section offset in d_out
constexpr int CAP_E = 48;          // max nodes per edge (P(>=48) ~ 1e-30)
constexpr int SIMT = 1024;         // sim block size (16 waves on one CU)
constexpr int NPT  = 10;           // nodes per thread (1024*10 >= 10000)

// ---- Threefry-2x32, 20 rounds (exact JAX semantics), host+device ----
__host__ __device__ inline void tf2x32(uint32_t k0, uint32_t k1,
                                       uint32_t x0, uint32_t x1,
                                       uint32_t &o0, uint32_t &o1) {
  uint32_t ks2 = k0 ^ k1 ^ 0x1BD11BDAu;
  x0 += k0; x1 += k1;
#define TFR(r) do { x0 += x1; x1 = (x1 << (r)) | (x1 >> (32 - (r))); x1 ^= x0; } while (0)
  TFR(13); TFR(15); TFR(26); TFR(6);
  x0 += k1;  x1 += ks2 + 1u;
  TFR(17); TFR(29); TFR(16); TFR(24);
  x0 += ks2; x1 += k0 + 2u;
  TFR(13); TFR(15); TFR(26); TFR(6);
  x0 += k0;  x1 += k1 + 3u;
  TFR(17); TFR(29); TFR(16); TFR(24);
  x0 += k1;  x1 += ks2 + 4u;
  TFR(13); TFR(15); TFR(26); TFR(6);
  x0 += ks2; x1 += k0 + 5u;
#undef TFR
  o0 = x0; o1 = x1;
}

__device__ inline float bits_to_uniform(uint32_t bits) {
  float f = __uint_as_float((bits >> 9) | 0x3F800000u) - 1.0f;
  return f < 0.f ? 0.f : f;
}

struct StepKeys { uint32_t k1a[TS], k1b[TS], k2a[TS], k2b[TS]; };

// precompute ALL uniforms (state-independent): u1[t][n], u2[t][n]
__global__ void k_rand(float* __restrict__ u1, float* __restrict__ u2, StepKeys keys) {
  int t = blockIdx.y;
  int n = blockIdx.x * blockDim.x + threadIdx.x;
  if (n >= NN) return;
  uint32_t a, b;
  tf2x32(keys.k1a[t], keys.k1b[t], 0u, (uint32_t)n, a, b);
  u1[t * NN + n] = bits_to_uniform(a ^ b);
  tf2x32(keys.k2a[t], keys.k2b[t], 0u, (uint32_t)n, a, b);
  u2[t * NN + n] = bits_to_uniform(a ^ b);
}

// edge->node lists, stored TRANSPOSED: edge_nodes[(t*CAP_E + m)*EE + e] = m-th member of e
__global__ void k_scan(const float* __restrict__ H, int* __restrict__ edge_cnt,
                       uint16_t* __restrict__ edge_nodes) {
  const int row = blockIdx.x;  // t*EE + e
  const int t = row / EE;
  const int e = row - t * EE;
  __shared__ int cnt;
  __shared__ uint16_t list[CAP_E];
  if (threadIdx.x == 0) cnt = 0;
  __syncthreads();
  const float4* hrow = reinterpret_cast<const float4*>(H + (size_t)row * NN);
  for (int i = threadIdx.x; i < NN / 4; i += blockDim.x) {
    float4 v = hrow[i];
    int b4 = i * 4;
    if (v.x != 0.f) { int p = atomicAdd(&cnt, 1); if (p < CAP_E) list[p] = (uint16_t)(b4 + 0); }
    if (v.y != 0.f) { int p = atomicAdd(&cnt, 1); if (p < CAP_E) list[p] = (uint16_t)(b4 + 1); }
    if (v.z != 0.f) { int p = atomicAdd(&cnt, 1); if (p < CAP_E) list[p] = (uint16_t)(b4 + 2); }
    if (v.w != 0.f) { int p = atomicAdd(&cnt, 1); if (p < CAP_E) list[p] = (uint16_t)(b4 + 3); }
  }
  __syncthreads();
  int c = cnt < CAP_E ? cnt : CAP_E;
  if (threadIdx.x == 0) edge_cnt[row] = c;
  if ((int)threadIdx.x < c)
    edge_nodes[((size_t)t * CAP_E + threadIdx.x) * EE + e] = list[threadIdx.x];
}

// ---- all 29 steps, one workgroup; p in regs, s in LDS; emits compact nv/st trace ----
__global__ __launch_bounds__(SIMT, 4)
void k_sim(const float* __restrict__ x,
           const int* __restrict__ edge_cnt, const uint16_t* __restrict__ edge_nodes,
           const float* __restrict__ u1, const float* __restrict__ u2,
           const float* __restrict__ beta, const float* __restrict__ gamma_,
           uint16_t* __restrict__ nvA, uint8_t* __restrict__ stA) {
  __shared__ uint8_t s_st[NN];   // 10 KB: state code 0=S 1=I 2=R
  __shared__ int nv[NN];         // 40 KB: per-node two-hop infected count (exact ints)
  const int tid = threadIdx.x;

  float p0[NPT], p1[NPT], p2[NPT], bet[NPT], gam[NPT];
#pragma unroll
  for (int k = 0; k < NPT; ++k) {
    int n = tid + k * SIMT;
    if (n < NN) {
      float x0 = x[n * 3 + 0], x1 = x[n * 3 + 1];
      p0[k] = x0; p1[k] = x1; p2[k] = x[n * 3 + 2];
      uint8_t c = (x1 == 1.f) ? 1 : ((x0 == 1.f) ? 0 : 2);
      s_st[n] = c;
      stA[n] = c;                 // stA row 0
      bet[k] = beta[n]; gam[k] = gamma_[n];
    }
  }
  __syncthreads();

  for (int t = 0; t < TS; ++t) {
#pragma unroll
    for (int k = 0; k < NPT; ++k) { int n = tid + k * SIMT; if (n < NN) nv[n] = 0; }
    __syncthreads();

    // edge phase: s_e = #infected members; scatter s_e into every member's nv
    if (tid < EE) {
      int row = t * EE + tid;
      int ec = edge_cnt[row];
      const uint16_t* base = edge_nodes + (size_t)t * CAP_E * EE + tid;
      int s = 0;
      for (int m = 0; m < ec; ++m) s += (s_st[base[(size_t)m * EE]] == 1) ? 1 : 0;
      for (int m = 0; m < ec; ++m) atomicAdd(&nv[base[(size_t)m * EE]], s);
    }
    __syncthreads();

    // node phase: advance p in regs, draw transitions, emit compact trace
    const float* u1t = u1 + (size_t)t * NN;
    const float* u2t = u2 + (size_t)t * NN;
    uint16_t* nvO = nvA + (size_t)t * NN;
    uint8_t*  stO = stA + (size_t)(t + 1) * NN;
#pragma unroll
    for (int k = 0; k < NPT; ++k) {
      int n = tid + k * SIMT;
      if (n < NN) {
        int st = s_st[n];
        int v = nv[n];
        float s1 = (st == 1) ? 1.f : 0.f;
        float new_cases = __fmul_rn(bet[k], (float)v);
        float new_rec   = __fmul_rn(gam[k], s1);
        float q0 = fminf(1.f, fmaxf(0.f, __fsub_rn(p0[k], new_cases)));
        float q1 = fminf(1.f, fmaxf(0.f, __fsub_rn(__fadd_rn(p1[k], new_cases), new_rec)));
        float q2 = fminf(1.f, fmaxf(0.f, __fadd_rn(p2[k], new_rec)));
        p0[k] = q0; p1[k] = q1; p2[k] = q2;

        float uu1 = u1t[n], uu2 = u2t[n];
        bool was_S  = (st == 0);
        bool was_I  = (st == 1);
        bool s_to_I = was_S && (uu1 < q1);
        bool i_event = was_I && (uu1 < q2);
        bool u2lt   = (uu2 < 0.5f);
        bool i_to_S = i_event && !u2lt;
        bool new_S = (was_S && !s_to_I) || i_to_S;
        bool new_I = s_to_I || (was_I && !i_event);
        uint8_t c = new_I ? 1 : (new_S ? 0 : 2);
        s_st[n] = c;
        stO[n] = c;
        nvO[n] = (uint16_t)v;
      }
    }
    __syncthreads();
  }
}

// full-chip: replay per-node p-chain (bit-identical ops) + write all output rows
__global__ void k_expand(float* __restrict__ out, const float* __restrict__ x,
                         const uint16_t* __restrict__ nvA, const uint8_t* __restrict__ stA,
                         const float* __restrict__ beta, const float* __restrict__ gamma_) {
  int n = blockIdx.x * blockDim.x + threadIdx.x;
  if (n >= NN) return;
  float p0 = x[n * 3 + 0], p1 = x[n * 3 + 1], p2 = x[n * 3 + 2];
  float bet = beta[n], gam = gamma_[n];
  // row 0 = x for both sections
  out[n * 3 + 0] = p0; out[n * 3 + 1] = p1; out[n * 3 + 2] = p2;
  out[S_OFF + n * 3 + 0] = p0; out[S_OFF + n * 3 + 1] = p1; out[S_OFF + n * 3 + 2] = p2;
  for (int t = 0; t < TS; ++t) {
    int st = stA[(size_t)t * NN + n];
    float s1 = (st == 1) ? 1.f : 0.f;
    float new_cases = __fmul_rn(bet, (float)nvA[(size_t)t * NN + n]);
    float new_rec   = __fmul_rn(gam, s1);
    p0 = fminf(1.f, fmaxf(0.f, __fsub_rn(p0, new_cases)));
    p1 = fminf(1.f, fmaxf(0.f, __fsub_rn(__fadd_rn(p1, new_cases), new_rec)));
    p2 = fminf(1.f, fmaxf(0.f, __fadd_rn(p2, new_rec)));
    float* po = out + (size_t)(t + 1) * ROW;
    float* so = out + S_OFF + (size_t)(t + 1) * ROW;
    po[n * 3 + 0] = p0; po[n * 3 + 1] = p1; po[n * 3 + 2] = p2;
    int sn = stA[(size_t)(t + 1) * NN + n];
    so[n * 3 + 0] = (sn == 0) ? 1.f : 0.f;
    so[n * 3 + 1] = (sn == 1) ? 1.f : 0.f;
    so[n * 3 + 2] = (sn == 2) ? 1.f : 0.f;
  }
}

extern "C" void kernel_launch(void* const* d_in, const int* in_sizes, int n_in,
                              void* d_out, int out_size, void* d_ws, size_t ws_size,
                              hipStream_t stream) {
  const float* x      = (const float*)d_in[0];
  const float* H      = (const float*)d_in[1];
  const float* beta   = (const float*)d_in[2];
  const float* gamma_ = (const float*)d_in[3];
  float* out = (float*)d_out;

  // key chain: key0 = jax.random.key(42) = (0,42); split(key,3) partitionable:
  // subkey i = threefry(key, (0,i)); carry = subkey 0.
  StepKeys keys;
  uint32_t key0 = 0u, key1 = 42u;
  for (int t = 0; t < TS; ++t) {
    uint32_t a0, b0, a1, b1, a2, b2;
    tf2x32(key0, key1, 0u, 0u, a0, b0);
    tf2x32(key0, key1, 0u, 1u, a1, b1);
    tf2x32(key0, key1, 0u, 2u, a2, b2);
    keys.k1a[t] = a1; keys.k1b[t] = b1; keys.k2a[t] = a2; keys.k2b[t] = b2;
    key0 = a0; key1 = b0;
  }

  // workspace layout (~6 MB)
  size_t off = 0;
  auto take = [&](size_t bytes) { size_t o = off; off += (bytes + 255) & ~(size_t)255; return o; };
  size_t o_ec = take((size_t)TS * EE * sizeof(int));
  size_t o_en = take((size_t)TS * EE * CAP_E * sizeof(uint16_t));
  size_t o_u1 = take((size_t)TS * NN * sizeof(float));
  size_t o_u2 = take((size_t)TS * NN * sizeof(float));
  size_t o_nv = take((size_t)TS * NN * sizeof(uint16_t));
  size_t o_st = take((size_t)TT * NN * sizeof(uint8_t));

  int*      edge_cnt   = (int*)((char*)d_ws + o_ec);
  uint16_t* edge_nodes = (uint16_t*)((char*)d_ws + o_en);
  float*    u1         = (float*)((char*)d_ws + o_u1);
  float*    u2         = (float*)((char*)d_ws + o_u2);
  uint16_t* nvA        = (uint16_t*)((char*)d_ws + o_nv);
  uint8_t*  stA        = (uint8_t*)((char*)d_ws + o_st);

  k_rand<<<dim3((NN + 255) / 256, TS), 256, 0, stream>>>(u1, u2, keys);
  k_scan<<<TS * EE, 256, 0, stream>>>(H, edge_cnt, edge_nodes);
  k_sim<<<1, SIMT, 0, stream>>>(x, edge_cnt, edge_nodes, u1, u2, beta, gamma_, nvA, stA);
  k_expand<<<(NN + 255) / 256, 256, 0, stream>>>(out, x, nvA, stA, beta, gamma_);
}